// Round 2
// baseline (1431.752 us; speedup 1.0000x reference)
//
#include <hip/hip_runtime.h>
#include <hip/hip_bf16.h>
#include <float.h>
#include <math.h>

#define HH 16
#define DH 64
#define NS 1024
#define NB 2
#define DIMM 1024
#define SCALE 0.125f
#define KTOP 32
#define NEGF (-FLT_MAX)

// ---------------- K1: QKV projection GEMM ----------------
// C[2048][3072] = x @ [Wq | Wkv]; scatter into q,k,v (b,h,n,d)
__global__ __launch_bounds__(256) void k1_qkv(const float* __restrict__ x,
        const float* __restrict__ Wq, const float* __restrict__ Wkv,
        float* __restrict__ q, float* __restrict__ k, float* __restrict__ v) {
    __shared__ float As[64][17];
    __shared__ float Bs[16][68];
    int t = threadIdx.x;
    int col0 = blockIdx.x * 64;     // 0..3071
    int row0 = blockIdx.y * 64;     // 0..2047
    int tr = t >> 4, tc = t & 15;
    float acc[4][4] = {};
    const float* Bbase; int ldb; int bcol;
    if (col0 < 1024) { Bbase = Wq;  ldb = 1024; bcol = col0; }
    else             { Bbase = Wkv; ldb = 2048; bcol = col0 - 1024; }
    for (int k0 = 0; k0 < 1024; k0 += 16) {
        for (int e = 0; e < 4; ++e) {
            int f = t + 256*e; int r = f >> 4, kk = f & 15;
            As[r][kk] = x[(row0 + r)*1024 + k0 + kk];
        }
        for (int e = 0; e < 4; ++e) {
            int f = t + 256*e; int kk = f >> 6, cc = f & 63;
            Bs[kk][cc] = Bbase[(k0 + kk)*ldb + bcol + cc];
        }
        __syncthreads();
        #pragma unroll
        for (int kk = 0; kk < 16; ++kk) {
            float a[4], bb[4];
            #pragma unroll
            for (int i2 = 0; i2 < 4; ++i2) a[i2] = As[tr*4+i2][kk];
            #pragma unroll
            for (int j2 = 0; j2 < 4; ++j2) bb[j2] = Bs[kk][tc*4+j2];
            #pragma unroll
            for (int i2 = 0; i2 < 4; ++i2)
                #pragma unroll
                for (int j2 = 0; j2 < 4; ++j2) acc[i2][j2] += a[i2]*bb[j2];
        }
        __syncthreads();
    }
    #pragma unroll
    for (int i2 = 0; i2 < 4; ++i2)
        #pragma unroll
        for (int j2 = 0; j2 < 4; ++j2) {
            int row = row0 + tr*4 + i2;
            int col = col0 + tc*4 + j2;
            int b_ = row >> 10, i = row & 1023;
            int which = col >> 10; int cc = col & 1023;
            int h = cc >> 6, d = cc & 63;
            float* dst = (which == 0) ? q : ((which == 1) ? k : v);
            dst[(((b_*HH) + h)*NS + i)*DH + d] = acc[i2][j2];
        }
}

// ---------------- K2: scores for all heads + pre-softmax talking-heads mix ----------------
// one block per (b, lower-tri 32x32 tile). writes mixed dots[b][k'][i][j] (j-tile <= i-tile)
__global__ __launch_bounds__(256) void k2_scores(const float* __restrict__ q,
        const float* __restrict__ k, const float* __restrict__ rel,
        const float* __restrict__ pre, float* __restrict__ dots) {
    __shared__ float qs[32][65];
    __shared__ float ks[32][65];
    __shared__ float sc[HH][32][33];
    __shared__ float preS[HH][HH];
    int t = threadIdx.x;
    int b_ = blockIdx.y;
    int lin = blockIdx.x;  // 0..527
    int ti = (int)((sqrtf(8.0f*(float)lin + 1.0f) - 1.0f) * 0.5f);
    while ((ti+1)*(ti+2)/2 <= lin) ++ti;
    while (ti*(ti+1)/2 > lin) --ti;
    int tj = lin - ti*(ti+1)/2;
    int i0 = ti*32, j0 = tj*32;
    preS[t >> 4][t & 15] = pre[t];
    int r8 = t >> 3, c4 = (t & 7) * 4;
    for (int h = 0; h < HH; ++h) {
        for (int e = 0; e < 8; ++e) {
            int f = t + 256*e; int r = f >> 6, d = f & 63;
            qs[r][d] = q[(((b_*HH) + h)*NS + (i0 + r))*DH + d];
            ks[r][d] = k[(((b_*HH) + h)*NS + (j0 + r))*DH + d];
        }
        __syncthreads();
        float a0 = 0, a1 = 0, a2 = 0, a3 = 0;
        #pragma unroll
        for (int d = 0; d < DH; ++d) {
            float qa = qs[r8][d];
            a0 += qa * ks[c4+0][d];
            a1 += qa * ks[c4+1][d];
            a2 += qa * ks[c4+2][d];
            a3 += qa * ks[c4+3][d];
        }
        sc[h][r8][c4+0] = a0; sc[h][r8][c4+1] = a1;
        sc[h][r8][c4+2] = a2; sc[h][r8][c4+3] = a3;
        __syncthreads();
    }
    // mix: mixed[k'] = sum_h (s[h]*SCALE + rel[h]) * pre[h][k']
    for (int j = 0; j < 4; ++j) {
        int r = r8, c = c4 + j;
        int gi = i0 + r, gj = j0 + c;
        float tv[HH];
        #pragma unroll
        for (int h = 0; h < HH; ++h)
            tv[h] = sc[h][r][c] * SCALE + rel[(h*NS + gi)*NS + gj];
        #pragma unroll
        for (int kp = 0; kp < HH; ++kp) {
            float o = 0;
            #pragma unroll
            for (int h = 0; h < HH; ++h) o += tv[h] * preS[h][kp];
            dots[(((b_*HH) + kp)*NS + gi)*NS + gj] = o;
        }
    }
}

// ---------------- K3: causal mask + top-k threshold + softmax + post-mix (in place) ----------------
// one block per (b,i): stages 16 head-rows, wave-per-head topk+softmax, then head mix
__global__ __launch_bounds__(256) void k3_topk(float* __restrict__ dots,
        const float* __restrict__ post) {
    __shared__ float sc[HH][NS];   // 64 KB
    __shared__ float postS[HH][HH];
    int t = threadIdx.x;
    int bi = blockIdx.x;
    int b_ = bi >> 10, i = bi & 1023;
    postS[t >> 4][t & 15] = post[t];
    for (int e = 0; e < 64; ++e) {
        int f = t + 256*e;
        int h = f >> 10, j = f & 1023;
        sc[h][j] = dots[(((b_*HH) + h)*NS + i)*NS + j];
    }
    __syncthreads();
    int w = t >> 6, l = t & 63;
    for (int hq = 0; hq < 4; ++hq) {
        int h = w*4 + hq;
        float vals[16];
        #pragma unroll
        for (int s = 0; s < 16; ++s) {
            int j = l + 64*s;
            vals[s] = (j <= i) ? sc[h][j] : NEGF;
        }
        float m = NEGF;
        #pragma unroll
        for (int s = 0; s < 16; ++s) m = fmaxf(m, vals[s]);
        #pragma unroll
        for (int o = 32; o; o >>= 1) m = fmaxf(m, __shfl_xor(m, o));
        // 32 max-extractions -> threshold = 32nd largest (distinct; exact fp32 keeps ref tie rule)
        float thr = FLT_MAX;
        for (int it = 0; it < KTOP; ++it) {
            float loc = -INFINITY;
            #pragma unroll
            for (int s = 0; s < 16; ++s) {
                float vv = vals[s];
                loc = (vv < thr) ? fmaxf(loc, vv) : loc;
            }
            #pragma unroll
            for (int o = 32; o; o >>= 1) loc = fmaxf(loc, __shfl_xor(loc, o));
            thr = loc;
        }
        float e_[16]; float ssum = 0;
        #pragma unroll
        for (int s = 0; s < 16; ++s) {
            float vv = vals[s];
            float ev = (vv >= thr) ? __expf(vv - m) : 0.0f;
            e_[s] = ev; ssum += ev;
        }
        #pragma unroll
        for (int o = 32; o; o >>= 1) ssum += __shfl_xor(ssum, o);
        float inv = 1.0f / ssum;
        #pragma unroll
        for (int s = 0; s < 16; ++s) sc[h][l + 64*s] = e_[s] * inv;
    }
    __syncthreads();
    // post-softmax talking-heads mix, write back to global (same (b,:,i,:) slab)
    for (int c = 0; c < 4; ++c) {
        int j = t + 256*c;
        float a16[HH];
        #pragma unroll
        for (int h = 0; h < HH; ++h) a16[h] = sc[h][j];
        #pragma unroll
        for (int kp = 0; kp < HH; ++kp) {
            float o = 0;
            #pragma unroll
            for (int h = 0; h < HH; ++h) o += a16[h] * postS[h][kp];
            dots[(((b_*HH) + kp)*NS + i)*NS + j] = o;
        }
    }
}

// ---------------- K5: PV batched GEMM (causal tile skip) ----------------
__global__ __launch_bounds__(256) void k5_pv(const float* __restrict__ dots,
        const float* __restrict__ v, float* __restrict__ ao) {
    __shared__ float As[64][65];
    __shared__ float Bs[64][68];
    int t = threadIdx.x;
    int bh = blockIdx.y;            // 0..31 (b*16+k')
    int i0 = blockIdx.x * 64;
    int tr = t >> 4, tc = t & 15;
    float acc[4][4] = {};
    int jtmax = (i0 + 63) >> 6;
    for (int jt = 0; jt <= jtmax; ++jt) {
        int j0 = jt * 64;
        for (int e = 0; e < 16; ++e) {
            int f = t + 256*e; int r = f >> 6, cc = f & 63;
            As[r][cc] = dots[(bh*NS + (i0 + r))*NS + j0 + cc];
            Bs[r][cc] = v[(bh*NS + (j0 + r))*DH + cc];
        }
        __syncthreads();
        #pragma unroll
        for (int kk = 0; kk < 64; ++kk) {
            float a[4], bb[4];
            #pragma unroll
            for (int i2 = 0; i2 < 4; ++i2) a[i2] = As[tr*4+i2][kk];
            #pragma unroll
            for (int j2 = 0; j2 < 4; ++j2) bb[j2] = Bs[kk][tc*4+j2];
            #pragma unroll
            for (int i2 = 0; i2 < 4; ++i2)
                #pragma unroll
                for (int j2 = 0; j2 < 4; ++j2) acc[i2][j2] += a[i2]*bb[j2];
        }
        __syncthreads();
    }
    #pragma unroll
    for (int i2 = 0; i2 < 4; ++i2)
        #pragma unroll
        for (int j2 = 0; j2 < 4; ++j2)
            ao[(bh*NS + (i0 + tr*4 + i2))*DH + tc*4 + j2] = acc[i2][j2];
}

// ---------------- K6: output projection ----------------
__global__ __launch_bounds__(256) void k6_outproj(const float* __restrict__ ao,
        const float* __restrict__ Wout, const float* __restrict__ bout,
        float* __restrict__ y) {
    __shared__ float As[64][17];
    __shared__ float Bs[16][68];
    int t = threadIdx.x;
    int col0 = blockIdx.x * 64;     // 0..1023
    int row0 = blockIdx.y * 64;     // 0..2047
    int tr = t >> 4, tc = t & 15;
    float acc[4][4] = {};
    for (int k0 = 0; k0 < 1024; k0 += 16) {
        for (int e = 0; e < 4; ++e) {
            int f = t + 256*e; int r = f >> 4, kk = f & 15;
            int row = row0 + r; int b_ = row >> 10, i = row & 1023;
            int m = k0 + kk; int h = m >> 6, d = m & 63;
            As[r][kk] = ao[(((b_*HH) + h)*NS + i)*DH + d];
        }
        for (int e = 0; e < 4; ++e) {
            int f = t + 256*e; int kk = f >> 6, cc = f & 63;
            Bs[kk][cc] = Wout[(k0 + kk)*1024 + col0 + cc];
        }
        __syncthreads();
        #pragma unroll
        for (int kk = 0; kk < 16; ++kk) {
            float a[4], bb[4];
            #pragma unroll
            for (int i2 = 0; i2 < 4; ++i2) a[i2] = As[tr*4+i2][kk];
            #pragma unroll
            for (int j2 = 0; j2 < 4; ++j2) bb[j2] = Bs[kk][tc*4+j2];
            #pragma unroll
            for (int i2 = 0; i2 < 4; ++i2)
                #pragma unroll
                for (int j2 = 0; j2 < 4; ++j2) acc[i2][j2] += a[i2]*bb[j2];
        }
        __syncthreads();
    }
    #pragma unroll
    for (int i2 = 0; i2 < 4; ++i2)
        #pragma unroll
        for (int j2 = 0; j2 < 4; ++j2) {
            int row = row0 + tr*4 + i2, col = col0 + tc*4 + j2;
            y[row*1024 + col] = acc[i2][j2] + bout[col];
        }
}

extern "C" void kernel_launch(void* const* d_in, const int* in_sizes, int n_in,
                              void* d_out, int out_size, void* d_ws, size_t ws_size,
                              hipStream_t stream) {
    const float* x    = (const float*)d_in[0];
    const float* rel  = (const float*)d_in[1];
    const float* Wq   = (const float*)d_in[2];
    const float* Wkv  = (const float*)d_in[3];
    const float* pre  = (const float*)d_in[4];
    const float* post = (const float*)d_in[5];
    const float* Wout = (const float*)d_in[6];
    const float* bout = (const float*)d_in[7];
    float* out = (float*)d_out;

    float* ws   = (float*)d_ws;
    float* q    = ws;                 // 2,097,152
    float* kbuf = ws + 2097152;       // 2,097,152
    float* vbuf = ws + 4194304;       // 2,097,152
    float* ao   = ws + 6291456;       // 2,097,152
    float* dots = ws + 8388608;       // 33,554,432  (total 160 MiB)

    k1_qkv<<<dim3(48, 32), 256, 0, stream>>>(x, Wq, Wkv, q, kbuf, vbuf);
    k2_scores<<<dim3(528, 2), 256, 0, stream>>>(q, kbuf, rel, pre, dots);
    k3_topk<<<dim3(2048), 256, 0, stream>>>(dots, post);
    k5_pv<<<dim3(16, 32), 256, 0, stream>>>(dots, vbuf, ao);
    k6_outproj<<<dim3(16, 32), 256, 0, stream>>>(ao, Wout, bout, out);
}

// Round 5
// 785.151 us; speedup vs baseline: 1.8235x; 1.8235x over previous
//
#include <hip/hip_runtime.h>
#include <hip/hip_bf16.h>
#include <float.h>
#include <math.h>

#define HH 16
#define DH 64
#define NS 1024
#define SCALE 0.125f
#define KTOP 32
#define NEGF (-FLT_MAX)

typedef __attribute__((ext_vector_type(8))) short short8;
typedef __attribute__((ext_vector_type(4))) float f32x4;
typedef unsigned short ushort_t;

__device__ __forceinline__ ushort_t f2b(float f) {
    __hip_bfloat16 h = __float2bfloat16(f);
    return *reinterpret_cast<ushort_t*>(&h);
}

// ---------------- K0a: f32 -> bf16 convert (x) ----------------
__global__ __launch_bounds__(256) void k0_cvt(const float* __restrict__ src,
        ushort_t* __restrict__ dst, int n8) {
    int i = blockIdx.x * 256 + threadIdx.x;
    if (i >= n8) return;
    const float4* s4 = (const float4*)src;
    float4 a = s4[i*2], b = s4[i*2+1];
    short8 o;
    o[0]=f2b(a.x); o[1]=f2b(a.y); o[2]=f2b(a.z); o[3]=f2b(a.w);
    o[4]=f2b(b.x); o[5]=f2b(b.y); o[6]=f2b(b.z); o[7]=f2b(b.w);
    *(short8*)(dst + i*8) = o;
}

// ---------------- K0b: f32 [K=1024][N] -> bf16 transposed [N][1024] ----------------
__global__ __launch_bounds__(256) void k0_tr(const float* __restrict__ src,
        ushort_t* __restrict__ dst, int N) {
    __shared__ float sh[32][33];
    int tx = threadIdx.x & 31, ty = threadIdx.x >> 5;
    int n0 = blockIdx.x * 32, k0 = blockIdx.y * 32;
    #pragma unroll
    for (int e = 0; e < 4; ++e) {
        int r = ty + e*8;
        sh[r][tx] = src[(k0 + r)*N + n0 + tx];
    }
    __syncthreads();
    #pragma unroll
    for (int e = 0; e < 4; ++e) {
        int r = ty + e*8;
        dst[(n0 + r)*1024 + k0 + tx] = f2b(sh[tx][r]);
    }
}

// ---------------- K1: QKV projection, bf16 MFMA 128x128 tile ----------------
// xb[2048][1024] @ Wt^T (Wt bf16 [3072 n][1024 k]) -> q bf16, k bf16, v f32
__global__ __launch_bounds__(256) void k1_mfma(const ushort_t* __restrict__ xb,
        const ushort_t* __restrict__ Wt, ushort_t* __restrict__ qb,
        ushort_t* __restrict__ kbf, float* __restrict__ vf) {
    __shared__ ushort_t As[128*40];   // rows padded to 40 (2-way bank, free)
    __shared__ ushort_t Bs[128*40];
    int t = threadIdx.x;
    int lane = t & 63, w = t >> 6;
    int wm = w >> 1, wn = w & 1;
    int row_l = lane & 15, grp = lane >> 4;
    int row0 = blockIdx.y * 128, col0 = blockIdx.x * 128;
    f32x4 acc[4][4];
    f32x4 zz = {0.f, 0.f, 0.f, 0.f};
    #pragma unroll
    for (int mi = 0; mi < 4; ++mi)
        #pragma unroll
        for (int ni = 0; ni < 4; ++ni) acc[mi][ni] = zz;
    for (int k0 = 0; k0 < 1024; k0 += 32) {
        #pragma unroll
        for (int e = 0; e < 2; ++e) {
            int slot = t + 256*e;
            int r = slot >> 2, kbk = slot & 3;
            short8 vA = *(const short8*)(xb + (row0 + r)*1024 + k0 + kbk*8);
            *(short8*)(As + r*40 + kbk*8) = vA;
            short8 vB = *(const short8*)(Wt + (col0 + r)*1024 + k0 + kbk*8);
            *(short8*)(Bs + r*40 + kbk*8) = vB;
        }
        __syncthreads();
        short8 a[4], b[4];
        #pragma unroll
        for (int mi = 0; mi < 4; ++mi)
            a[mi] = *(const short8*)(As + (wm*64 + mi*16 + row_l)*40 + grp*8);
        #pragma unroll
        for (int ni = 0; ni < 4; ++ni)
            b[ni] = *(const short8*)(Bs + (wn*64 + ni*16 + row_l)*40 + grp*8);
        #pragma unroll
        for (int mi = 0; mi < 4; ++mi)
            #pragma unroll
            for (int ni = 0; ni < 4; ++ni)
                acc[mi][ni] = __builtin_amdgcn_mfma_f32_16x16x32_bf16(
                    a[mi], b[ni], acc[mi][ni], 0, 0, 0);
        __syncthreads();
    }
    #pragma unroll
    for (int mi = 0; mi < 4; ++mi)
        #pragma unroll
        for (int ni = 0; ni < 4; ++ni)
            #pragma unroll
            for (int rg = 0; rg < 4; ++rg) {
                int grow = row0 + wm*64 + mi*16 + grp*4 + rg;
                int gcol = col0 + wn*64 + ni*16 + row_l;
                float val = acc[mi][ni][rg];
                int b_ = grow >> 10, i = grow & 1023;
                int which = gcol >> 10, cc = gcol & 1023;
                int h = cc >> 6, d = cc & 63;
                int idx = (((b_*HH + h)*NS) + i)*DH + d;
                if (which == 0)      qb[idx]  = f2b(val);
                else if (which == 1) kbf[idx] = f2b(val);
                else                 vf[idx]  = val;
            }
}

// ---------------- K2: scores (MFMA) + pre-softmax talking-heads mix, one wave per 16x16 tile ----------------
__global__ __launch_bounds__(256) void k2_scores(const ushort_t* __restrict__ qb,
        const ushort_t* __restrict__ kbf, const float* __restrict__ rel,
        const float* __restrict__ pre, float* __restrict__ dots) {
    int t = threadIdx.x & 63;
    int w = threadIdx.x >> 6;
    int wid = blockIdx.x * 4 + w;          // 0..4159
    int b_ = (wid >= 2080) ? 1 : 0;
    int r = wid - 2080*b_;
    int i16 = (int)((sqrtf(8.0f*(float)r + 1.0f) - 1.0f) * 0.5f);
    while ((i16+1)*(i16+2)/2 <= r) ++i16;
    while (i16*(i16+1)/2 > r) --i16;
    int j16 = r - i16*(i16+1)/2;
    int row_l = t & 15, grp = t >> 4;
    int qrow = i16*16 + row_l;
    int krow = j16*16 + row_l;
    int dbase = grp*8;
    float acc[16][4];
    #pragma unroll
    for (int kp = 0; kp < 16; ++kp)
        #pragma unroll
        for (int rg = 0; rg < 4; ++rg) acc[kp][rg] = 0.f;
    #pragma unroll 4
    for (int h = 0; h < HH; ++h) {
        const ushort_t* qh = qb + (((b_*HH + h)*NS) + qrow)*DH;
        const ushort_t* kh = kbf + (((b_*HH + h)*NS) + krow)*DH;
        short8 a0 = *(const short8*)(qh + dbase);
        short8 a1 = *(const short8*)(qh + 32 + dbase);
        short8 b0 = *(const short8*)(kh + dbase);
        short8 b1 = *(const short8*)(kh + 32 + dbase);
        f32x4 s = {0.f, 0.f, 0.f, 0.f};
        s = __builtin_amdgcn_mfma_f32_16x16x32_bf16(a0, b0, s, 0, 0, 0);
        s = __builtin_amdgcn_mfma_f32_16x16x32_bf16(a1, b1, s, 0, 0, 0);
        float pr[16];
        #pragma unroll
        for (int kp = 0; kp < 16; ++kp) pr[kp] = pre[h*16 + kp];
        #pragma unroll
        for (int rg = 0; rg < 4; ++rg) {
            int gi = i16*16 + grp*4 + rg;
            int gj = j16*16 + row_l;
            float tv = s[rg]*SCALE + rel[(h*NS + gi)*NS + gj];
            #pragma unroll
            for (int kp = 0; kp < 16; ++kp) acc[kp][rg] += tv * pr[kp];
        }
    }
    int gj = j16*16 + row_l;
    #pragma unroll
    for (int kp = 0; kp < 16; ++kp)
        #pragma unroll
        for (int rg = 0; rg < 4; ++rg) {
            int gi = i16*16 + grp*4 + rg;
            dots[(((b_*HH + kp)*NS) + gi)*NS + gj] = acc[kp][rg];
        }
}

// ---------------- K3: causal mask + top-k threshold + softmax + post-mix (in place) ----------------
__global__ __launch_bounds__(256) void k3_topk(float* __restrict__ dots,
        const float* __restrict__ post) {
    __shared__ float sc[HH][NS];   // 64 KB
    __shared__ float postS[HH][HH];
    int t = threadIdx.x;
    int bi = blockIdx.x;
    int b_ = bi >> 10, i = bi & 1023;
    postS[t >> 4][t & 15] = post[t];
    for (int e = 0; e < 64; ++e) {
        int f = t + 256*e;
        int h = f >> 10, j = f & 1023;
        sc[h][j] = dots[(((b_*HH) + h)*NS + i)*NS + j];
    }
    __syncthreads();
    int w = t >> 6, l = t & 63;
    for (int hq = 0; hq < 4; ++hq) {
        int h = w*4 + hq;
        float vals[16];
        #pragma unroll
        for (int s = 0; s < 16; ++s) {
            int j = l + 64*s;
            vals[s] = (j <= i) ? sc[h][j] : NEGF;
        }
        float m = NEGF;
        #pragma unroll
        for (int s = 0; s < 16; ++s) m = fmaxf(m, vals[s]);
        #pragma unroll
        for (int o = 32; o; o >>= 1) m = fmaxf(m, __shfl_xor(m, o));
        float thr = FLT_MAX;
        for (int it = 0; it < KTOP; ++it) {
            float loc = -INFINITY;
            #pragma unroll
            for (int s = 0; s < 16; ++s) {
                float vv = vals[s];
                loc = (vv < thr) ? fmaxf(loc, vv) : loc;
            }
            #pragma unroll
            for (int o = 32; o; o >>= 1) loc = fmaxf(loc, __shfl_xor(loc, o));
            thr = loc;
        }
        float e_[16]; float ssum = 0;
        #pragma unroll
        for (int s = 0; s < 16; ++s) {
            float vv = vals[s];
            float ev = (vv >= thr) ? __expf(vv - m) : 0.0f;
            e_[s] = ev; ssum += ev;
        }
        #pragma unroll
        for (int o = 32; o; o >>= 1) ssum += __shfl_xor(ssum, o);
        float inv = 1.0f / ssum;
        #pragma unroll
        for (int s = 0; s < 16; ++s) sc[h][l + 64*s] = e_[s] * inv;
    }
    __syncthreads();
    for (int c = 0; c < 4; ++c) {
        int j = t + 256*c;
        float a16[HH];
        #pragma unroll
        for (int h = 0; h < HH; ++h) a16[h] = sc[h][j];
        #pragma unroll
        for (int kp = 0; kp < HH; ++kp) {
            float o = 0;
            #pragma unroll
            for (int h = 0; h < HH; ++h) o += a16[h] * postS[h][kp];
            dots[(((b_*HH) + kp)*NS + i)*NS + j] = o;
        }
    }
}

// ---------------- K5: PV batched GEMM (causal tile skip), ao out bf16 ----------------
__global__ __launch_bounds__(256) void k5_pv(const float* __restrict__ dots,
        const float* __restrict__ v, ushort_t* __restrict__ ao) {
    __shared__ float As[64][65];
    __shared__ float Bs[64][68];
    int t = threadIdx.x;
    int bh = blockIdx.y;
    int i0 = blockIdx.x * 64;
    int tr = t >> 4, tc = t & 15;
    float acc[4][4] = {};
    int jtmax = (i0 + 63) >> 6;
    for (int jt = 0; jt <= jtmax; ++jt) {
        int j0 = jt * 64;
        for (int e = 0; e < 16; ++e) {
            int f = t + 256*e; int r = f >> 6, cc = f & 63;
            As[r][cc] = dots[(bh*NS + (i0 + r))*NS + j0 + cc];
            Bs[r][cc] = v[(bh*NS + (j0 + r))*DH + cc];
        }
        __syncthreads();
        #pragma unroll
        for (int kk = 0; kk < 64; ++kk) {
            float a[4], bb[4];
            #pragma unroll
            for (int i2 = 0; i2 < 4; ++i2) a[i2] = As[tr*4+i2][kk];
            #pragma unroll
            for (int j2 = 0; j2 < 4; ++j2) bb[j2] = Bs[kk][tc*4+j2];
            #pragma unroll
            for (int i2 = 0; i2 < 4; ++i2)
                #pragma unroll
                for (int j2 = 0; j2 < 4; ++j2) acc[i2][j2] += a[i2]*bb[j2];
        }
        __syncthreads();
    }
    #pragma unroll
    for (int i2 = 0; i2 < 4; ++i2)
        #pragma unroll
        for (int j2 = 0; j2 < 4; ++j2)
            ao[(bh*NS + (i0 + tr*4 + i2))*DH + tc*4 + j2] = f2b(acc[i2][j2]);
}

// ---------------- K6: output projection, bf16 MFMA ----------------
__global__ __launch_bounds__(256) void k6_mfma(const ushort_t* __restrict__ aob,
        const ushort_t* __restrict__ Wot, const float* __restrict__ bout,
        float* __restrict__ y) {
    __shared__ ushort_t As[128*40];
    __shared__ ushort_t Bs[128*40];
    int t = threadIdx.x;
    int lane = t & 63, w = t >> 6;
    int wm = w >> 1, wn = w & 1;
    int row_l = lane & 15, grp = lane >> 4;
    int row0 = blockIdx.y * 128, col0 = blockIdx.x * 128;
    f32x4 acc[4][4];
    f32x4 zz = {0.f, 0.f, 0.f, 0.f};
    #pragma unroll
    for (int mi = 0; mi < 4; ++mi)
        #pragma unroll
        for (int ni = 0; ni < 4; ++ni) acc[mi][ni] = zz;
    for (int k0 = 0; k0 < 1024; k0 += 32) {
        #pragma unroll
        for (int e = 0; e < 2; ++e) {
            int slot = t + 256*e;
            int r = slot >> 2, kbk = slot & 3;
            int grow = row0 + r;
            int b_ = grow >> 10, i = grow & 1023;
            int kk0 = k0 + kbk*8;
            int h = kk0 >> 6, d = kk0 & 63;
            short8 vA = *(const short8*)(aob + (((b_*HH + h)*NS) + i)*DH + d);
            *(short8*)(As + r*40 + kbk*8) = vA;
            short8 vB = *(const short8*)(Wot + (col0 + r)*1024 + k0 + kbk*8);
            *(short8*)(Bs + r*40 + kbk*8) = vB;
        }
        __syncthreads();
        short8 a[4], b[4];
        #pragma unroll
        for (int mi = 0; mi < 4; ++mi)
            a[mi] = *(const short8*)(As + (wm*64 + mi*16 + row_l)*40 + grp*8);
        #pragma unroll
        for (int ni = 0; ni < 4; ++ni)
            b[ni] = *(const short8*)(Bs + (wn*64 + ni*16 + row_l)*40 + grp*8);
        #pragma unroll
        for (int mi = 0; mi < 4; ++mi)
            #pragma unroll
            for (int ni = 0; ni < 4; ++ni)
                acc[mi][ni] = __builtin_amdgcn_mfma_f32_16x16x32_bf16(
                    a[mi], b[ni], acc[mi][ni], 0, 0, 0);
        __syncthreads();
    }
    #pragma unroll
    for (int mi = 0; mi < 4; ++mi)
        #pragma unroll
        for (int ni = 0; ni < 4; ++ni)
            #pragma unroll
            for (int rg = 0; rg < 4; ++rg) {
                int grow = row0 + wm*64 + mi*16 + grp*4 + rg;
                int gcol = col0 + wn*64 + ni*16 + row_l;
                y[grow*1024 + gcol] = acc[mi][ni][rg] + bout[gcol];
            }
}

extern "C" void kernel_launch(void* const* d_in, const int* in_sizes, int n_in,
                              void* d_out, int out_size, void* d_ws, size_t ws_size,
                              hipStream_t stream) {
    const float* x    = (const float*)d_in[0];
    const float* rel  = (const float*)d_in[1];
    const float* Wq   = (const float*)d_in[2];
    const float* Wkv  = (const float*)d_in[3];
    const float* pre  = (const float*)d_in[4];
    const float* post = (const float*)d_in[5];
    const float* Wout = (const float*)d_in[6];
    const float* bout = (const float*)d_in[7];
    float* out = (float*)d_out;

    float* ws = (float*)d_ws;
    // float-unit offsets (total exactly 160 MiB)
    float*    dots = ws;                               // 33,554,432 f
    float*    vbuf = ws + 33554432;                    //  2,097,152 f
    ushort_t* qb   = (ushort_t*)(ws + 35651584);       //  2,097,152 bf16
    ushort_t* kbuf = (ushort_t*)(ws + 36700160);       //  2,097,152 bf16
    ushort_t* xb   = (ushort_t*)(ws + 37748736);       //  2,097,152 bf16
    ushort_t* Wt   = (ushort_t*)(ws + 38797312);       //  3,145,728 bf16
    ushort_t* Wot  = (ushort_t*)(ws + 40370176);       //  1,048,576 bf16
    ushort_t* aob  = (ushort_t*)(ws + 40894464);       //  2,097,152 bf16

    k0_cvt<<<1024, 256, 0, stream>>>(x, xb, 262144);
    k0_tr<<<dim3(32, 32), 256, 0, stream>>>(Wq, Wt, 1024);
    k0_tr<<<dim3(64, 32), 256, 0, stream>>>(Wkv, Wt + 1024*1024, 2048);
    k0_tr<<<dim3(32, 32), 256, 0, stream>>>(Wout, Wot, 1024);
    k1_mfma<<<dim3(24, 16), 256, 0, stream>>>(xb, Wt, qb, kbuf, vbuf);
    k2_scores<<<dim3(1040), 256, 0, stream>>>(qb, kbuf, rel, pre, dots);
    k3_topk<<<dim3(2048), 256, 0, stream>>>(dots, post);
    k5_pv<<<dim3(16, 32), 256, 0, stream>>>(dots, vbuf, aob);
    k6_mfma<<<dim3(8, 16), 256, 0, stream>>>(aob, Wot, bout, out);
}

// Round 6
// 431.691 us; speedup vs baseline: 3.3166x; 1.8188x over previous
//
#include <hip/hip_runtime.h>
#include <hip/hip_bf16.h>
#include <float.h>
#include <math.h>

#define HH 16
#define DH 64
#define NS 1024
#define SCALE 0.125f
#define KTOP 32
#define NEGF (-FLT_MAX)

typedef __attribute__((ext_vector_type(8))) short short8;
typedef __attribute__((ext_vector_type(4))) float f32x4;
typedef unsigned short ushort_t;

__device__ __forceinline__ ushort_t f2b(float f) {
    __hip_bfloat16 h = __float2bfloat16(f);
    return *reinterpret_cast<ushort_t*>(&h);
}

// ---------------- K0a: f32 -> bf16 convert (x) ----------------
__global__ __launch_bounds__(256) void k0_cvt(const float* __restrict__ src,
        ushort_t* __restrict__ dst, int n8) {
    int i = blockIdx.x * 256 + threadIdx.x;
    if (i >= n8) return;
    const float4* s4 = (const float4*)src;
    float4 a = s4[i*2], b = s4[i*2+1];
    short8 o;
    o[0]=f2b(a.x); o[1]=f2b(a.y); o[2]=f2b(a.z); o[3]=f2b(a.w);
    o[4]=f2b(b.x); o[5]=f2b(b.y); o[6]=f2b(b.z); o[7]=f2b(b.w);
    *(short8*)(dst + i*8) = o;
}

// ---------------- K0b: f32 [K=1024][N] -> bf16 transposed [N][1024] ----------------
__global__ __launch_bounds__(256) void k0_tr(const float* __restrict__ src,
        ushort_t* __restrict__ dst, int N) {
    __shared__ float sh[32][33];
    int tx = threadIdx.x & 31, ty = threadIdx.x >> 5;
    int n0 = blockIdx.x * 32, k0 = blockIdx.y * 32;
    #pragma unroll
    for (int e = 0; e < 4; ++e) {
        int r = ty + e*8;
        sh[r][tx] = src[(k0 + r)*N + n0 + tx];
    }
    __syncthreads();
    #pragma unroll
    for (int e = 0; e < 4; ++e) {
        int r = ty + e*8;
        dst[(n0 + r)*1024 + k0 + tx] = f2b(sh[tx][r]);
    }
}

// ---------------- K1: QKV projection, bf16 MFMA 128x128 tile ----------------
__global__ __launch_bounds__(256) void k1_mfma(const ushort_t* __restrict__ xb,
        const ushort_t* __restrict__ Wt, ushort_t* __restrict__ qb,
        ushort_t* __restrict__ kbf, float* __restrict__ vf) {
    __shared__ ushort_t As[128*40];
    __shared__ ushort_t Bs[128*40];
    int t = threadIdx.x;
    int lane = t & 63, w = t >> 6;
    int wm = w >> 1, wn = w & 1;
    int row_l = lane & 15, grp = lane >> 4;
    int row0 = blockIdx.y * 128, col0 = blockIdx.x * 128;
    f32x4 acc[4][4];
    f32x4 zz = {0.f, 0.f, 0.f, 0.f};
    #pragma unroll
    for (int mi = 0; mi < 4; ++mi)
        #pragma unroll
        for (int ni = 0; ni < 4; ++ni) acc[mi][ni] = zz;
    for (int k0 = 0; k0 < 1024; k0 += 32) {
        #pragma unroll
        for (int e = 0; e < 2; ++e) {
            int slot = t + 256*e;
            int r = slot >> 2, kbk = slot & 3;
            short8 vA = *(const short8*)(xb + (row0 + r)*1024 + k0 + kbk*8);
            *(short8*)(As + r*40 + kbk*8) = vA;
            short8 vB = *(const short8*)(Wt + (col0 + r)*1024 + k0 + kbk*8);
            *(short8*)(Bs + r*40 + kbk*8) = vB;
        }
        __syncthreads();
        short8 a[4], b[4];
        #pragma unroll
        for (int mi = 0; mi < 4; ++mi)
            a[mi] = *(const short8*)(As + (wm*64 + mi*16 + row_l)*40 + grp*8);
        #pragma unroll
        for (int ni = 0; ni < 4; ++ni)
            b[ni] = *(const short8*)(Bs + (wn*64 + ni*16 + row_l)*40 + grp*8);
        #pragma unroll
        for (int mi = 0; mi < 4; ++mi)
            #pragma unroll
            for (int ni = 0; ni < 4; ++ni)
                acc[mi][ni] = __builtin_amdgcn_mfma_f32_16x16x32_bf16(
                    a[mi], b[ni], acc[mi][ni], 0, 0, 0);
        __syncthreads();
    }
    #pragma unroll
    for (int mi = 0; mi < 4; ++mi)
        #pragma unroll
        for (int ni = 0; ni < 4; ++ni)
            #pragma unroll
            for (int rg = 0; rg < 4; ++rg) {
                int grow = row0 + wm*64 + mi*16 + grp*4 + rg;
                int gcol = col0 + wn*64 + ni*16 + row_l;
                float val = acc[mi][ni][rg];
                int b_ = grow >> 10, i = grow & 1023;
                int which = gcol >> 10, cc = gcol & 1023;
                int h = cc >> 6, d = cc & 63;
                int idx = (((b_*HH + h)*NS) + i)*DH + d;
                if (which == 0)      qb[idx]  = f2b(val);
                else if (which == 1) kbf[idx] = f2b(val);
                else                 vf[idx]  = val;
            }
}

// ---------------- K2: scores (MFMA) + pre-softmax talking-heads mix ----------------
__global__ __launch_bounds__(256) void k2_scores(const ushort_t* __restrict__ qb,
        const ushort_t* __restrict__ kbf, const float* __restrict__ rel,
        const float* __restrict__ pre, float* __restrict__ dots) {
    int t = threadIdx.x & 63;
    int w = threadIdx.x >> 6;
    int wid = blockIdx.x * 4 + w;
    int b_ = (wid >= 2080) ? 1 : 0;
    int r = wid - 2080*b_;
    int i16 = (int)((sqrtf(8.0f*(float)r + 1.0f) - 1.0f) * 0.5f);
    while ((i16+1)*(i16+2)/2 <= r) ++i16;
    while (i16*(i16+1)/2 > r) --i16;
    int j16 = r - i16*(i16+1)/2;
    int row_l = t & 15, grp = t >> 4;
    int qrow = i16*16 + row_l;
    int krow = j16*16 + row_l;
    int dbase = grp*8;
    float acc[16][4];
    #pragma unroll
    for (int kp = 0; kp < 16; ++kp)
        #pragma unroll
        for (int rg = 0; rg < 4; ++rg) acc[kp][rg] = 0.f;
    #pragma unroll 4
    for (int h = 0; h < HH; ++h) {
        const ushort_t* qh = qb + (((b_*HH + h)*NS) + qrow)*DH;
        const ushort_t* kh = kbf + (((b_*HH + h)*NS) + krow)*DH;
        short8 a0 = *(const short8*)(qh + dbase);
        short8 a1 = *(const short8*)(qh + 32 + dbase);
        short8 b0 = *(const short8*)(kh + dbase);
        short8 b1 = *(const short8*)(kh + 32 + dbase);
        f32x4 s = {0.f, 0.f, 0.f, 0.f};
        s = __builtin_amdgcn_mfma_f32_16x16x32_bf16(a0, b0, s, 0, 0, 0);
        s = __builtin_amdgcn_mfma_f32_16x16x32_bf16(a1, b1, s, 0, 0, 0);
        float pr[16];
        #pragma unroll
        for (int kp = 0; kp < 16; ++kp) pr[kp] = pre[h*16 + kp];
        #pragma unroll
        for (int rg = 0; rg < 4; ++rg) {
            int gi = i16*16 + grp*4 + rg;
            int gj = j16*16 + row_l;
            float tv = s[rg]*SCALE + rel[(h*NS + gi)*NS + gj];
            #pragma unroll
            for (int kp = 0; kp < 16; ++kp) acc[kp][rg] += tv * pr[kp];
        }
    }
    int gj = j16*16 + row_l;
    #pragma unroll
    for (int kp = 0; kp < 16; ++kp)
        #pragma unroll
        for (int rg = 0; rg < 4; ++rg) {
            int gi = i16*16 + grp*4 + rg;
            dots[(((b_*HH + kp)*NS) + gi)*NS + gj] = acc[kp][rg];
        }
}

// ---------------- K3 helper: per-wave causal mask + top-k + softmax -> LDS probs ----------------
template<int NC>
__device__ __forceinline__ void topk_row(const float* __restrict__ rowp,
        float* __restrict__ scRow, int i, int l) {
    float4 v[NC];
    #pragma unroll
    for (int c = 0; c < NC; ++c)
        v[c] = *(const float4*)(rowp + c*256 + l*4);
    #pragma unroll
    for (int c = 0; c < NC; ++c) {
        int j0 = c*256 + l*4;
        if (j0 + 0 > i) v[c].x = NEGF;
        if (j0 + 1 > i) v[c].y = NEGF;
        if (j0 + 2 > i) v[c].z = NEGF;
        if (j0 + 3 > i) v[c].w = NEGF;
    }
    float m = NEGF;
    #pragma unroll
    for (int c = 0; c < NC; ++c)
        m = fmaxf(m, fmaxf(fmaxf(v[c].x, v[c].y), fmaxf(v[c].z, v[c].w)));
    #pragma unroll
    for (int o = 32; o; o >>= 1) m = fmaxf(m, __shfl_xor(m, o));
    float thr = FLT_MAX;
    for (int it = 0; it < KTOP; ++it) {
        float loc = -INFINITY;
        #pragma unroll
        for (int c = 0; c < NC; ++c) {
            loc = (v[c].x < thr) ? fmaxf(loc, v[c].x) : loc;
            loc = (v[c].y < thr) ? fmaxf(loc, v[c].y) : loc;
            loc = (v[c].z < thr) ? fmaxf(loc, v[c].z) : loc;
            loc = (v[c].w < thr) ? fmaxf(loc, v[c].w) : loc;
        }
        #pragma unroll
        for (int o = 32; o; o >>= 1) loc = fmaxf(loc, __shfl_xor(loc, o));
        thr = loc;
    }
    float ssum = 0.f;
    #pragma unroll
    for (int c = 0; c < NC; ++c) {
        v[c].x = (v[c].x >= thr) ? __expf(v[c].x - m) : 0.f; ssum += v[c].x;
        v[c].y = (v[c].y >= thr) ? __expf(v[c].y - m) : 0.f; ssum += v[c].y;
        v[c].z = (v[c].z >= thr) ? __expf(v[c].z - m) : 0.f; ssum += v[c].z;
        v[c].w = (v[c].w >= thr) ? __expf(v[c].w - m) : 0.f; ssum += v[c].w;
    }
    #pragma unroll
    for (int o = 32; o; o >>= 1) ssum += __shfl_xor(ssum, o);
    float inv = 1.0f / ssum;
    #pragma unroll
    for (int c = 0; c < NC; ++c) {
        float4 o4;
        o4.x = v[c].x * inv; o4.y = v[c].y * inv;
        o4.z = v[c].z * inv; o4.w = v[c].w * inv;
        *(float4*)(scRow + c*256 + l*4) = o4;
    }
    float4 z4 = {0.f, 0.f, 0.f, 0.f};
    #pragma unroll
    for (int c = NC; c < 4; ++c)
        *(float4*)(scRow + c*256 + l*4) = z4;
}

// ---------------- K3: one block per (b,i); one wave per head; post-mix fused ----------------
__global__ __launch_bounds__(1024, 4) void k3_topk(float* __restrict__ dots,
        const float* __restrict__ post) {
    __shared__ float sc[HH][NS];   // 64 KB probs
    __shared__ float postS[HH][HH];
    int t = threadIdx.x;
    int bi = blockIdx.x;
    int b_ = bi >> 10, i = bi & 1023;
    if (t < 256) postS[t >> 4][t & 15] = post[t];
    int w = t >> 6;      // head
    int l = t & 63;      // lane
    const float* rowp = dots + ((size_t)((b_*HH + w)*NS + i))*NS;
    int nc = (i >> 8) + 1;
    if (nc == 1)      topk_row<1>(rowp, sc[w], i, l);
    else if (nc == 2) topk_row<2>(rowp, sc[w], i, l);
    else if (nc == 3) topk_row<3>(rowp, sc[w], i, l);
    else              topk_row<4>(rowp, sc[w], i, l);
    __syncthreads();
    // post-softmax talking-heads mix: thread t handles column j = t
    float a16[HH];
    #pragma unroll
    for (int h = 0; h < HH; ++h) a16[h] = sc[h][t];
    #pragma unroll
    for (int kp = 0; kp < HH; ++kp) {
        float o = 0.f;
        #pragma unroll
        for (int h = 0; h < HH; ++h) o += a16[h] * postS[h][kp];
        dots[(((b_*HH) + kp)*NS + i)*NS + t] = o;
    }
}

// ---------------- K5: PV batched GEMM (causal tile skip), ao out bf16 ----------------
__global__ __launch_bounds__(256) void k5_pv(const float* __restrict__ dots,
        const float* __restrict__ v, ushort_t* __restrict__ ao) {
    __shared__ float As[64][65];
    __shared__ float Bs[64][68];
    int t = threadIdx.x;
    int bh = blockIdx.y;
    int i0 = blockIdx.x * 64;
    int tr = t >> 4, tc = t & 15;
    float acc[4][4] = {};
    int jtmax = (i0 + 63) >> 6;
    for (int jt = 0; jt <= jtmax; ++jt) {
        int j0 = jt * 64;
        for (int e = 0; e < 16; ++e) {
            int f = t + 256*e; int r = f >> 6, cc = f & 63;
            As[r][cc] = dots[(bh*NS + (i0 + r))*NS + j0 + cc];
            Bs[r][cc] = v[(bh*NS + (j0 + r))*DH + cc];
        }
        __syncthreads();
        #pragma unroll
        for (int kk = 0; kk < 64; ++kk) {
            float a[4], bb[4];
            #pragma unroll
            for (int i2 = 0; i2 < 4; ++i2) a[i2] = As[tr*4+i2][kk];
            #pragma unroll
            for (int j2 = 0; j2 < 4; ++j2) bb[j2] = Bs[kk][tc*4+j2];
            #pragma unroll
            for (int i2 = 0; i2 < 4; ++i2)
                #pragma unroll
                for (int j2 = 0; j2 < 4; ++j2) acc[i2][j2] += a[i2]*bb[j2];
        }
        __syncthreads();
    }
    #pragma unroll
    for (int i2 = 0; i2 < 4; ++i2)
        #pragma unroll
        for (int j2 = 0; j2 < 4; ++j2)
            ao[(bh*NS + (i0 + tr*4 + i2))*DH + tc*4 + j2] = f2b(acc[i2][j2]);
}

// ---------------- K6: output projection, bf16 MFMA ----------------
__global__ __launch_bounds__(256) void k6_mfma(const ushort_t* __restrict__ aob,
        const ushort_t* __restrict__ Wot, const float* __restrict__ bout,
        float* __restrict__ y) {
    __shared__ ushort_t As[128*40];
    __shared__ ushort_t Bs[128*40];
    int t = threadIdx.x;
    int lane = t & 63, w = t >> 6;
    int wm = w >> 1, wn = w & 1;
    int row_l = lane & 15, grp = lane >> 4;
    int row0 = blockIdx.y * 128, col0 = blockIdx.x * 128;
    f32x4 acc[4][4];
    f32x4 zz = {0.f, 0.f, 0.f, 0.f};
    #pragma unroll
    for (int mi = 0; mi < 4; ++mi)
        #pragma unroll
        for (int ni = 0; ni < 4; ++ni) acc[mi][ni] = zz;
    for (int k0 = 0; k0 < 1024; k0 += 32) {
        #pragma unroll
        for (int e = 0; e < 2; ++e) {
            int slot = t + 256*e;
            int r = slot >> 2, kbk = slot & 3;
            int grow = row0 + r;
            int b_ = grow >> 10, i = grow & 1023;
            int kk0 = k0 + kbk*8;
            int h = kk0 >> 6, d = kk0 & 63;
            short8 vA = *(const short8*)(aob + (((b_*HH + h)*NS) + i)*DH + d);
            *(short8*)(As + r*40 + kbk*8) = vA;
            short8 vB = *(const short8*)(Wot + (col0 + r)*1024 + k0 + kbk*8);
            *(short8*)(Bs + r*40 + kbk*8) = vB;
        }
        __syncthreads();
        short8 a[4], b[4];
        #pragma unroll
        for (int mi = 0; mi < 4; ++mi)
            a[mi] = *(const short8*)(As + (wm*64 + mi*16 + row_l)*40 + grp*8);
        #pragma unroll
        for (int ni = 0; ni < 4; ++ni)
            b[ni] = *(const short8*)(Bs + (wn*64 + ni*16 + row_l)*40 + grp*8);
        #pragma unroll
        for (int mi = 0; mi < 4; ++mi)
            #pragma unroll
            for (int ni = 0; ni < 4; ++ni)
                acc[mi][ni] = __builtin_amdgcn_mfma_f32_16x16x32_bf16(
                    a[mi], b[ni], acc[mi][ni], 0, 0, 0);
        __syncthreads();
    }
    #pragma unroll
    for (int mi = 0; mi < 4; ++mi)
        #pragma unroll
        for (int ni = 0; ni < 4; ++ni)
            #pragma unroll
            for (int rg = 0; rg < 4; ++rg) {
                int grow = row0 + wm*64 + mi*16 + grp*4 + rg;
                int gcol = col0 + wn*64 + ni*16 + row_l;
                y[grow*1024 + gcol] = acc[mi][ni][rg] + bout[gcol];
            }
}

extern "C" void kernel_launch(void* const* d_in, const int* in_sizes, int n_in,
                              void* d_out, int out_size, void* d_ws, size_t ws_size,
                              hipStream_t stream) {
    const float* x    = (const float*)d_in[0];
    const float* rel  = (const float*)d_in[1];
    const float* Wq   = (const float*)d_in[2];
    const float* Wkv  = (const float*)d_in[3];
    const float* pre  = (const float*)d_in[4];
    const float* post = (const float*)d_in[5];
    const float* Wout = (const float*)d_in[6];
    const float* bout = (const float*)d_in[7];
    float* out = (float*)d_out;

    float* ws = (float*)d_ws;
    float*    dots = ws;                               // 33,554,432 f
    float*    vbuf = ws + 33554432;                    //  2,097,152 f
    ushort_t* qb   = (ushort_t*)(ws + 35651584);       //  2,097,152 bf16
    ushort_t* kbuf = (ushort_t*)(ws + 36700160);       //  2,097,152 bf16
    ushort_t* xb   = (ushort_t*)(ws + 37748736);       //  2,097,152 bf16
    ushort_t* Wt   = (ushort_t*)(ws + 38797312);       //  3,145,728 bf16
    ushort_t* Wot  = (ushort_t*)(ws + 40370176);       //  1,048,576 bf16
    ushort_t* aob  = (ushort_t*)(ws + 40894464);       //  2,097,152 bf16

    k0_cvt<<<1024, 256, 0, stream>>>(x, xb, 262144);
    k0_tr<<<dim3(32, 32), 256, 0, stream>>>(Wq, Wt, 1024);
    k0_tr<<<dim3(64, 32), 256, 0, stream>>>(Wkv, Wt + 1024*1024, 2048);
    k0_tr<<<dim3(32, 32), 256, 0, stream>>>(Wout, Wot, 1024);
    k1_mfma<<<dim3(24, 16), 256, 0, stream>>>(xb, Wt, qb, kbuf, vbuf);
    k2_scores<<<dim3(1040), 256, 0, stream>>>(qb, kbuf, rel, pre, dots);
    k3_topk<<<dim3(2048), 1024, 0, stream>>>(dots, post);
    k5_pv<<<dim3(16, 32), 256, 0, stream>>>(dots, vbuf, aob);
    k6_mfma<<<dim3(8, 16), 256, 0, stream>>>(aob, Wot, bout, out);
}

// Round 7
// 396.826 us; speedup vs baseline: 3.6080x; 1.0879x over previous
//
#include <hip/hip_runtime.h>
#include <hip/hip_bf16.h>
#include <float.h>
#include <math.h>

#define HH 16
#define DH 64
#define NS 1024
#define SCALE 0.125f
#define KTOP 32
#define NEGF (-FLT_MAX)

typedef __attribute__((ext_vector_type(8))) short short8;
typedef __attribute__((ext_vector_type(4))) float f32x4;
typedef unsigned short ushort_t;

__device__ __forceinline__ ushort_t f2b(float f) {
    __hip_bfloat16 h = __float2bfloat16(f);
    return *reinterpret_cast<ushort_t*>(&h);
}

// ---------------- K0a: f32 -> bf16 convert (x) ----------------
__global__ __launch_bounds__(256) void k0_cvt(const float* __restrict__ src,
        ushort_t* __restrict__ dst, int n8) {
    int i = blockIdx.x * 256 + threadIdx.x;
    if (i >= n8) return;
    const float4* s4 = (const float4*)src;
    float4 a = s4[i*2], b = s4[i*2+1];
    short8 o;
    o[0]=f2b(a.x); o[1]=f2b(a.y); o[2]=f2b(a.z); o[3]=f2b(a.w);
    o[4]=f2b(b.x); o[5]=f2b(b.y); o[6]=f2b(b.z); o[7]=f2b(b.w);
    *(short8*)(dst + i*8) = o;
}

// ---------------- K0b: f32 [K=1024][N] -> bf16 transposed [N][1024] ----------------
__global__ __launch_bounds__(256) void k0_tr(const float* __restrict__ src,
        ushort_t* __restrict__ dst, int N) {
    __shared__ float sh[32][33];
    int tx = threadIdx.x & 31, ty = threadIdx.x >> 5;
    int n0 = blockIdx.x * 32, k0 = blockIdx.y * 32;
    #pragma unroll
    for (int e = 0; e < 4; ++e) {
        int r = ty + e*8;
        sh[r][tx] = src[(k0 + r)*N + n0 + tx];
    }
    __syncthreads();
    #pragma unroll
    for (int e = 0; e < 4; ++e) {
        int r = ty + e*8;
        dst[(n0 + r)*1024 + k0 + tx] = f2b(sh[tx][r]);
    }
}

// ---------------- K1: QKV projection, bf16 MFMA 128x128 tile ----------------
// out: q bf16, k bf16, v bf16 (all (b,h,i,d))
__global__ __launch_bounds__(256) void k1_mfma(const ushort_t* __restrict__ xb,
        const ushort_t* __restrict__ Wt, ushort_t* __restrict__ qb,
        ushort_t* __restrict__ kbf, ushort_t* __restrict__ vb) {
    __shared__ ushort_t As[128*40];
    __shared__ ushort_t Bs[128*40];
    int t = threadIdx.x;
    int lane = t & 63, w = t >> 6;
    int wm = w >> 1, wn = w & 1;
    int row_l = lane & 15, grp = lane >> 4;
    int row0 = blockIdx.y * 128, col0 = blockIdx.x * 128;
    f32x4 acc[4][4];
    f32x4 zz = {0.f, 0.f, 0.f, 0.f};
    #pragma unroll
    for (int mi = 0; mi < 4; ++mi)
        #pragma unroll
        for (int ni = 0; ni < 4; ++ni) acc[mi][ni] = zz;
    for (int k0 = 0; k0 < 1024; k0 += 32) {
        #pragma unroll
        for (int e = 0; e < 2; ++e) {
            int slot = t + 256*e;
            int r = slot >> 2, kbk = slot & 3;
            short8 vA = *(const short8*)(xb + (row0 + r)*1024 + k0 + kbk*8);
            *(short8*)(As + r*40 + kbk*8) = vA;
            short8 vB = *(const short8*)(Wt + (col0 + r)*1024 + k0 + kbk*8);
            *(short8*)(Bs + r*40 + kbk*8) = vB;
        }
        __syncthreads();
        short8 a[4], b[4];
        #pragma unroll
        for (int mi = 0; mi < 4; ++mi)
            a[mi] = *(const short8*)(As + (wm*64 + mi*16 + row_l)*40 + grp*8);
        #pragma unroll
        for (int ni = 0; ni < 4; ++ni)
            b[ni] = *(const short8*)(Bs + (wn*64 + ni*16 + row_l)*40 + grp*8);
        #pragma unroll
        for (int mi = 0; mi < 4; ++mi)
            #pragma unroll
            for (int ni = 0; ni < 4; ++ni)
                acc[mi][ni] = __builtin_amdgcn_mfma_f32_16x16x32_bf16(
                    a[mi], b[ni], acc[mi][ni], 0, 0, 0);
        __syncthreads();
    }
    #pragma unroll
    for (int mi = 0; mi < 4; ++mi)
        #pragma unroll
        for (int ni = 0; ni < 4; ++ni)
            #pragma unroll
            for (int rg = 0; rg < 4; ++rg) {
                int grow = row0 + wm*64 + mi*16 + grp*4 + rg;
                int gcol = col0 + wn*64 + ni*16 + row_l;
                float val = acc[mi][ni][rg];
                int b_ = grow >> 10, i = grow & 1023;
                int which = gcol >> 10, cc = gcol & 1023;
                int h = cc >> 6, d = cc & 63;
                int idx = (((b_*HH + h)*NS) + i)*DH + d;
                if (which == 0)      qb[idx]  = f2b(val);
                else if (which == 1) kbf[idx] = f2b(val);
                else                 vb[idx]  = f2b(val);
            }
}

// ---------------- K4: v (b,h,i,d) bf16 -> vT (b,h,d,i) bf16 ----------------
__global__ __launch_bounds__(256) void k4_vt(const ushort_t* __restrict__ vb,
        ushort_t* __restrict__ vT) {
    __shared__ ushort_t sh[32][33];
    int bh = blockIdx.z;
    int d0 = blockIdx.x * 32;
    int i0 = blockIdx.y * 32;
    int tx = threadIdx.x & 31, ty = threadIdx.x >> 5;
    #pragma unroll
    for (int e = 0; e < 4; ++e) {
        int r = ty + e*8;
        sh[r][tx] = vb[((size_t)bh*NS + i0 + r)*DH + d0 + tx];
    }
    __syncthreads();
    #pragma unroll
    for (int e = 0; e < 4; ++e) {
        int r = ty + e*8;
        vT[((size_t)bh*DH + d0 + r)*NS + i0 + tx] = sh[tx][r];
    }
}

// ---------------- K2: scores (MFMA) + pre-softmax talking-heads mix ----------------
__global__ __launch_bounds__(256) void k2_scores(const ushort_t* __restrict__ qb,
        const ushort_t* __restrict__ kbf, const float* __restrict__ rel,
        const float* __restrict__ pre, float* __restrict__ dots) {
    int t = threadIdx.x & 63;
    int w = threadIdx.x >> 6;
    int wid = blockIdx.x * 4 + w;
    int b_ = (wid >= 2080) ? 1 : 0;
    int r = wid - 2080*b_;
    int i16 = (int)((sqrtf(8.0f*(float)r + 1.0f) - 1.0f) * 0.5f);
    while ((i16+1)*(i16+2)/2 <= r) ++i16;
    while (i16*(i16+1)/2 > r) --i16;
    int j16 = r - i16*(i16+1)/2;
    int row_l = t & 15, grp = t >> 4;
    int qrow = i16*16 + row_l;
    int krow = j16*16 + row_l;
    int dbase = grp*8;
    float acc[16][4];
    #pragma unroll
    for (int kp = 0; kp < 16; ++kp)
        #pragma unroll
        for (int rg = 0; rg < 4; ++rg) acc[kp][rg] = 0.f;
    #pragma unroll 4
    for (int h = 0; h < HH; ++h) {
        const ushort_t* qh = qb + (((b_*HH + h)*NS) + qrow)*DH;
        const ushort_t* kh = kbf + (((b_*HH + h)*NS) + krow)*DH;
        short8 a0 = *(const short8*)(qh + dbase);
        short8 a1 = *(const short8*)(qh + 32 + dbase);
        short8 b0 = *(const short8*)(kh + dbase);
        short8 b1 = *(const short8*)(kh + 32 + dbase);
        f32x4 s = {0.f, 0.f, 0.f, 0.f};
        s = __builtin_amdgcn_mfma_f32_16x16x32_bf16(a0, b0, s, 0, 0, 0);
        s = __builtin_amdgcn_mfma_f32_16x16x32_bf16(a1, b1, s, 0, 0, 0);
        float pr[16];
        #pragma unroll
        for (int kp = 0; kp < 16; ++kp) pr[kp] = pre[h*16 + kp];
        #pragma unroll
        for (int rg = 0; rg < 4; ++rg) {
            int gi = i16*16 + grp*4 + rg;
            int gj = j16*16 + row_l;
            float tv = s[rg]*SCALE + rel[(h*NS + gi)*NS + gj];
            #pragma unroll
            for (int kp = 0; kp < 16; ++kp) acc[kp][rg] += tv * pr[kp];
        }
    }
    int gj = j16*16 + row_l;
    #pragma unroll
    for (int kp = 0; kp < 16; ++kp)
        #pragma unroll
        for (int rg = 0; rg < 4; ++rg) {
            int gi = i16*16 + grp*4 + rg;
            dots[(((b_*HH + kp)*NS) + gi)*NS + gj] = acc[kp][rg];
        }
}

// ---------------- K3 helper: per-wave causal mask + top-k + softmax -> LDS probs ----------------
template<int NC>
__device__ __forceinline__ void topk_row(const float* __restrict__ rowp,
        float* __restrict__ scRow, int i, int l) {
    float4 v[NC];
    #pragma unroll
    for (int c = 0; c < NC; ++c)
        v[c] = *(const float4*)(rowp + c*256 + l*4);
    #pragma unroll
    for (int c = 0; c < NC; ++c) {
        int j0 = c*256 + l*4;
        if (j0 + 0 > i) v[c].x = NEGF;
        if (j0 + 1 > i) v[c].y = NEGF;
        if (j0 + 2 > i) v[c].z = NEGF;
        if (j0 + 3 > i) v[c].w = NEGF;
    }
    float m = NEGF;
    #pragma unroll
    for (int c = 0; c < NC; ++c)
        m = fmaxf(m, fmaxf(fmaxf(v[c].x, v[c].y), fmaxf(v[c].z, v[c].w)));
    #pragma unroll
    for (int o = 32; o; o >>= 1) m = fmaxf(m, __shfl_xor(m, o));
    float thr = FLT_MAX;
    for (int it = 0; it < KTOP; ++it) {
        float loc = -INFINITY;
        #pragma unroll
        for (int c = 0; c < NC; ++c) {
            loc = (v[c].x < thr) ? fmaxf(loc, v[c].x) : loc;
            loc = (v[c].y < thr) ? fmaxf(loc, v[c].y) : loc;
            loc = (v[c].z < thr) ? fmaxf(loc, v[c].z) : loc;
            loc = (v[c].w < thr) ? fmaxf(loc, v[c].w) : loc;
        }
        #pragma unroll
        for (int o = 32; o; o >>= 1) loc = fmaxf(loc, __shfl_xor(loc, o));
        thr = loc;
    }
    float ssum = 0.f;
    #pragma unroll
    for (int c = 0; c < NC; ++c) {
        v[c].x = (v[c].x >= thr) ? __expf(v[c].x - m) : 0.f; ssum += v[c].x;
        v[c].y = (v[c].y >= thr) ? __expf(v[c].y - m) : 0.f; ssum += v[c].y;
        v[c].z = (v[c].z >= thr) ? __expf(v[c].z - m) : 0.f; ssum += v[c].z;
        v[c].w = (v[c].w >= thr) ? __expf(v[c].w - m) : 0.f; ssum += v[c].w;
    }
    #pragma unroll
    for (int o = 32; o; o >>= 1) ssum += __shfl_xor(ssum, o);
    float inv = 1.0f / ssum;
    #pragma unroll
    for (int c = 0; c < NC; ++c) {
        float4 o4;
        o4.x = v[c].x * inv; o4.y = v[c].y * inv;
        o4.z = v[c].z * inv; o4.w = v[c].w * inv;
        *(float4*)(scRow + c*256 + l*4) = o4;
    }
    float4 z4 = {0.f, 0.f, 0.f, 0.f};
    #pragma unroll
    for (int c = NC; c < 4; ++c)
        *(float4*)(scRow + c*256 + l*4) = z4;
}

// ---------------- K3: topk+softmax per head-wave; post-mix written bf16 packed in place ----------------
// bf16 P row (b,kp,i) occupies the FIRST 2048 bytes of the fp32 dots row (b,kp,i).
__global__ __launch_bounds__(1024, 4) void k3_topk(float* __restrict__ dots,
        const float* __restrict__ post) {
    __shared__ float sc[HH][NS];
    __shared__ float postS[HH][HH];
    int t = threadIdx.x;
    int bi = blockIdx.x;
    int b_ = bi >> 10, i = bi & 1023;
    if (t < 256) postS[t >> 4][t & 15] = post[t];
    int w = t >> 6;
    int l = t & 63;
    const float* rowp = dots + ((size_t)((b_*HH + w)*NS + i))*NS;
    int nc = (i >> 8) + 1;
    if (nc == 1)      topk_row<1>(rowp, sc[w], i, l);
    else if (nc == 2) topk_row<2>(rowp, sc[w], i, l);
    else if (nc == 3) topk_row<3>(rowp, sc[w], i, l);
    else              topk_row<4>(rowp, sc[w], i, l);
    __syncthreads();
    ushort_t* pb = (ushort_t*)dots;
    float a16[HH];
    #pragma unroll
    for (int h = 0; h < HH; ++h) a16[h] = sc[h][t];
    #pragma unroll
    for (int kp = 0; kp < HH; ++kp) {
        float o = 0.f;
        #pragma unroll
        for (int h = 0; h < HH; ++h) o += a16[h] * postS[h][kp];
        // packed row base (ushort units): fp32 row index * 2
        pb[(((size_t)(b_*HH + kp)*NS + i)*NS << 1) + t] = f2b(o);
    }
}

// ---------------- K5: PV via MFMA, A = packed bf16 P (global), B = vT (global) ----------------
__global__ __launch_bounds__(256) void k5_pv(const ushort_t* __restrict__ pb,
        const ushort_t* __restrict__ vT, ushort_t* __restrict__ ao) {
    int t = threadIdx.x;
    int lane = t & 63, w = t >> 6;
    int bh = blockIdx.y;
    int i0 = blockIdx.x * 64;
    int row_l = lane & 15, grp = lane >> 4;
    int irow = i0 + w*16 + row_l;
    // packed P row: ushort index = (fp32 row index)*2
    const ushort_t* pA = pb + (((size_t)bh*NS + irow)*NS << 1);
    const ushort_t* vB = vT + ((size_t)bh*DH + row_l)*NS;
    f32x4 acc[4];
    f32x4 zz = {0.f, 0.f, 0.f, 0.f};
    #pragma unroll
    for (int ni = 0; ni < 4; ++ni) acc[ni] = zz;
    int nsteps = (i0 + 64) >> 5;
    for (int s = 0; s < nsteps; ++s) {
        int j0 = s*32 + grp*8;
        short8 a = *(const short8*)(pA + j0);
        #pragma unroll
        for (int ni = 0; ni < 4; ++ni) {
            short8 b = *(const short8*)(vB + ni*16*NS + j0);
            acc[ni] = __builtin_amdgcn_mfma_f32_16x16x32_bf16(a, b, acc[ni], 0, 0, 0);
        }
    }
    #pragma unroll
    for (int ni = 0; ni < 4; ++ni)
        #pragma unroll
        for (int rg = 0; rg < 4; ++rg)
            ao[((size_t)bh*NS + i0 + w*16 + grp*4 + rg)*DH + ni*16 + row_l] = f2b(acc[ni][rg]);
}

// ---------------- K6: output projection, bf16 MFMA ----------------
__global__ __launch_bounds__(256) void k6_mfma(const ushort_t* __restrict__ aob,
        const ushort_t* __restrict__ Wot, const float* __restrict__ bout,
        float* __restrict__ y) {
    __shared__ ushort_t As[128*40];
    __shared__ ushort_t Bs[128*40];
    int t = threadIdx.x;
    int lane = t & 63, w = t >> 6;
    int wm = w >> 1, wn = w & 1;
    int row_l = lane & 15, grp = lane >> 4;
    int row0 = blockIdx.y * 128, col0 = blockIdx.x * 128;
    f32x4 acc[4][4];
    f32x4 zz = {0.f, 0.f, 0.f, 0.f};
    #pragma unroll
    for (int mi = 0; mi < 4; ++mi)
        #pragma unroll
        for (int ni = 0; ni < 4; ++ni) acc[mi][ni] = zz;
    for (int k0 = 0; k0 < 1024; k0 += 32) {
        #pragma unroll
        for (int e = 0; e < 2; ++e) {
            int slot = t + 256*e;
            int r = slot >> 2, kbk = slot & 3;
            int grow = row0 + r;
            int b_ = grow >> 10, i = grow & 1023;
            int kk0 = k0 + kbk*8;
            int h = kk0 >> 6, d = kk0 & 63;
            short8 vA = *(const short8*)(aob + (((b_*HH + h)*NS) + i)*DH + d);
            *(short8*)(As + r*40 + kbk*8) = vA;
            short8 vB = *(const short8*)(Wot + (col0 + r)*1024 + k0 + kbk*8);
            *(short8*)(Bs + r*40 + kbk*8) = vB;
        }
        __syncthreads();
        short8 a[4], b[4];
        #pragma unroll
        for (int mi = 0; mi < 4; ++mi)
            a[mi] = *(const short8*)(As + (wm*64 + mi*16 + row_l)*40 + grp*8);
        #pragma unroll
        for (int ni = 0; ni < 4; ++ni)
            b[ni] = *(const short8*)(Bs + (wn*64 + ni*16 + row_l)*40 + grp*8);
        #pragma unroll
        for (int mi = 0; mi < 4; ++mi)
            #pragma unroll
            for (int ni = 0; ni < 4; ++ni)
                acc[mi][ni] = __builtin_amdgcn_mfma_f32_16x16x32_bf16(
                    a[mi], b[ni], acc[mi][ni], 0, 0, 0);
        __syncthreads();
    }
    #pragma unroll
    for (int mi = 0; mi < 4; ++mi)
        #pragma unroll
        for (int ni = 0; ni < 4; ++ni)
            #pragma unroll
            for (int rg = 0; rg < 4; ++rg) {
                int grow = row0 + wm*64 + mi*16 + grp*4 + rg;
                int gcol = col0 + wn*64 + ni*16 + row_l;
                y[grow*1024 + gcol] = acc[mi][ni][rg] + bout[gcol];
            }
}

extern "C" void kernel_launch(void* const* d_in, const int* in_sizes, int n_in,
                              void* d_out, int out_size, void* d_ws, size_t ws_size,
                              hipStream_t stream) {
    const float* x    = (const float*)d_in[0];
    const float* rel  = (const float*)d_in[1];
    const float* Wq   = (const float*)d_in[2];
    const float* Wkv  = (const float*)d_in[3];
    const float* pre  = (const float*)d_in[4];
    const float* post = (const float*)d_in[5];
    const float* Wout = (const float*)d_in[6];
    const float* bout = (const float*)d_in[7];
    float* out = (float*)d_out;

    float* ws = (float*)d_ws;
    // float-unit offsets (total exactly 160 MiB)
    float*    dots = ws;                               // 33,554,432 fu (bf16 P packed in place)
    ushort_t* vb   = (ushort_t*)(ws + 33554432);       // 2,097,152 bf16 (1,048,576 fu)
    ushort_t* vT   = (ushort_t*)(ws + 34603008);       // 2,097,152 bf16
    ushort_t* qb   = (ushort_t*)(ws + 35651584);       // 2,097,152 bf16
    ushort_t* kbuf = (ushort_t*)(ws + 36700160);       // 2,097,152 bf16
    ushort_t* xb   = (ushort_t*)(ws + 37748736);       // 2,097,152 bf16
    ushort_t* Wt   = (ushort_t*)(ws + 38797312);       // 3,145,728 bf16
    ushort_t* Wot  = (ushort_t*)(ws + 40370176);       // 1,048,576 bf16
    ushort_t* aob  = (ushort_t*)(ws + 40894464);       // 2,097,152 bf16

    k0_cvt<<<1024, 256, 0, stream>>>(x, xb, 262144);
    k0_tr<<<dim3(32, 32), 256, 0, stream>>>(Wq, Wt, 1024);
    k0_tr<<<dim3(64, 32), 256, 0, stream>>>(Wkv, Wt + 1024*1024, 2048);
    k0_tr<<<dim3(32, 32), 256, 0, stream>>>(Wout, Wot, 1024);
    k1_mfma<<<dim3(24, 16), 256, 0, stream>>>(xb, Wt, qb, kbuf, vb);
    k4_vt<<<dim3(2, 32, 32), 256, 0, stream>>>(vb, vT);
    k2_scores<<<dim3(1040), 256, 0, stream>>>(qb, kbuf, rel, pre, dots);
    k3_topk<<<dim3(2048), 1024, 0, stream>>>(dots, post);
    k5_pv<<<dim3(16, 32), 256, 0, stream>>>((const ushort_t*)dots, vT, aob);
    k6_mfma<<<dim3(8, 16), 256, 0, stream>>>(aob, Wot, bout, out);
}

// Round 8
// 340.371 us; speedup vs baseline: 4.2064x; 1.1659x over previous
//
#include <hip/hip_runtime.h>
#include <hip/hip_bf16.h>
#include <float.h>
#include <math.h>

#define HH 16
#define DH 64
#define NS 1024
#define SCALE 0.125f
#define KTOP 32
#define NEGF (-FLT_MAX)

typedef __attribute__((ext_vector_type(8))) short short8;
typedef __attribute__((ext_vector_type(4))) float f32x4;
typedef unsigned short ushort_t;

__device__ __forceinline__ ushort_t f2b(float f) {
    __hip_bfloat16 h = __float2bfloat16(f);
    return *reinterpret_cast<ushort_t*>(&h);
}

// ---------------- K0a: f32 -> bf16 convert (x) ----------------
__global__ __launch_bounds__(256) void k0_cvt(const float* __restrict__ src,
        ushort_t* __restrict__ dst, int n8) {
    int i = blockIdx.x * 256 + threadIdx.x;
    if (i >= n8) return;
    const float4* s4 = (const float4*)src;
    float4 a = s4[i*2], b = s4[i*2+1];
    short8 o;
    o[0]=f2b(a.x); o[1]=f2b(a.y); o[2]=f2b(a.z); o[3]=f2b(a.w);
    o[4]=f2b(b.x); o[5]=f2b(b.y); o[6]=f2b(b.z); o[7]=f2b(b.w);
    *(short8*)(dst + i*8) = o;
}

// ---------------- K0b: f32 [K=1024][N] -> bf16 transposed [N][1024] ----------------
__global__ __launch_bounds__(256) void k0_tr(const float* __restrict__ src,
        ushort_t* __restrict__ dst, int N) {
    __shared__ float sh[32][33];
    int tx = threadIdx.x & 31, ty = threadIdx.x >> 5;
    int n0 = blockIdx.x * 32, k0 = blockIdx.y * 32;
    #pragma unroll
    for (int e = 0; e < 4; ++e) {
        int r = ty + e*8;
        sh[r][tx] = src[(k0 + r)*N + n0 + tx];
    }
    __syncthreads();
    #pragma unroll
    for (int e = 0; e < 4; ++e) {
        int r = ty + e*8;
        dst[(n0 + r)*1024 + k0 + tx] = f2b(sh[tx][r]);
    }
}

// ---------------- K1: QKV projection, bf16 MFMA 128x128 tile ----------------
// out: q bf16, k bf16, v bf16 (all (b,h,i,d))
__global__ __launch_bounds__(256) void k1_mfma(const ushort_t* __restrict__ xb,
        const ushort_t* __restrict__ Wt, ushort_t* __restrict__ qb,
        ushort_t* __restrict__ kbf, ushort_t* __restrict__ vb) {
    __shared__ ushort_t As[128*40];
    __shared__ ushort_t Bs[128*40];
    int t = threadIdx.x;
    int lane = t & 63, w = t >> 6;
    int wm = w >> 1, wn = w & 1;
    int row_l = lane & 15, grp = lane >> 4;
    int row0 = blockIdx.y * 128, col0 = blockIdx.x * 128;
    f32x4 acc[4][4];
    f32x4 zz = {0.f, 0.f, 0.f, 0.f};
    #pragma unroll
    for (int mi = 0; mi < 4; ++mi)
        #pragma unroll
        for (int ni = 0; ni < 4; ++ni) acc[mi][ni] = zz;
    for (int k0 = 0; k0 < 1024; k0 += 32) {
        #pragma unroll
        for (int e = 0; e < 2; ++e) {
            int slot = t + 256*e;
            int r = slot >> 2, kbk = slot & 3;
            short8 vA = *(const short8*)(xb + (row0 + r)*1024 + k0 + kbk*8);
            *(short8*)(As + r*40 + kbk*8) = vA;
            short8 vB = *(const short8*)(Wt + (col0 + r)*1024 + k0 + kbk*8);
            *(short8*)(Bs + r*40 + kbk*8) = vB;
        }
        __syncthreads();
        short8 a[4], b[4];
        #pragma unroll
        for (int mi = 0; mi < 4; ++mi)
            a[mi] = *(const short8*)(As + (wm*64 + mi*16 + row_l)*40 + grp*8);
        #pragma unroll
        for (int ni = 0; ni < 4; ++ni)
            b[ni] = *(const short8*)(Bs + (wn*64 + ni*16 + row_l)*40 + grp*8);
        #pragma unroll
        for (int mi = 0; mi < 4; ++mi)
            #pragma unroll
            for (int ni = 0; ni < 4; ++ni)
                acc[mi][ni] = __builtin_amdgcn_mfma_f32_16x16x32_bf16(
                    a[mi], b[ni], acc[mi][ni], 0, 0, 0);
        __syncthreads();
    }
    #pragma unroll
    for (int mi = 0; mi < 4; ++mi)
        #pragma unroll
        for (int ni = 0; ni < 4; ++ni)
            #pragma unroll
            for (int rg = 0; rg < 4; ++rg) {
                int grow = row0 + wm*64 + mi*16 + grp*4 + rg;
                int gcol = col0 + wn*64 + ni*16 + row_l;
                float val = acc[mi][ni][rg];
                int b_ = grow >> 10, i = grow & 1023;
                int which = gcol >> 10, cc = gcol & 1023;
                int h = cc >> 6, d = cc & 63;
                int idx = (((b_*HH + h)*NS) + i)*DH + d;
                if (which == 0)      qb[idx]  = f2b(val);
                else if (which == 1) kbf[idx] = f2b(val);
                else                 vb[idx]  = f2b(val);
            }
}

// ---------------- K4: v (b,h,i,d) bf16 -> vT (b,h,d,i) bf16 ----------------
__global__ __launch_bounds__(256) void k4_vt(const ushort_t* __restrict__ vb,
        ushort_t* __restrict__ vT) {
    __shared__ ushort_t sh[32][33];
    int bh = blockIdx.z;
    int d0 = blockIdx.x * 32;
    int i0 = blockIdx.y * 32;
    int tx = threadIdx.x & 31, ty = threadIdx.x >> 5;
    #pragma unroll
    for (int e = 0; e < 4; ++e) {
        int r = ty + e*8;
        sh[r][tx] = vb[((size_t)bh*NS + i0 + r)*DH + d0 + tx];
    }
    __syncthreads();
    #pragma unroll
    for (int e = 0; e < 4; ++e) {
        int r = ty + e*8;
        vT[((size_t)bh*DH + d0 + r)*NS + i0 + tx] = sh[tx][r];
    }
}

// ---------------- K2: scores (MFMA) + pre-softmax talking-heads mix ----------------
__global__ __launch_bounds__(256) void k2_scores(const ushort_t* __restrict__ qb,
        const ushort_t* __restrict__ kbf, const float* __restrict__ rel,
        const float* __restrict__ pre, float* __restrict__ dots) {
    int t = threadIdx.x & 63;
    int w = threadIdx.x >> 6;
    int wid = blockIdx.x * 4 + w;
    int b_ = (wid >= 2080) ? 1 : 0;
    int r = wid - 2080*b_;
    int i16 = (int)((sqrtf(8.0f*(float)r + 1.0f) - 1.0f) * 0.5f);
    while ((i16+1)*(i16+2)/2 <= r) ++i16;
    while (i16*(i16+1)/2 > r) --i16;
    int j16 = r - i16*(i16+1)/2;
    int row_l = t & 15, grp = t >> 4;
    int qrow = i16*16 + row_l;
    int krow = j16*16 + row_l;
    int dbase = grp*8;
    float acc[16][4];
    #pragma unroll
    for (int kp = 0; kp < 16; ++kp)
        #pragma unroll
        for (int rg = 0; rg < 4; ++rg) acc[kp][rg] = 0.f;
    #pragma unroll 4
    for (int h = 0; h < HH; ++h) {
        const ushort_t* qh = qb + (((b_*HH + h)*NS) + qrow)*DH;
        const ushort_t* kh = kbf + (((b_*HH + h)*NS) + krow)*DH;
        short8 a0 = *(const short8*)(qh + dbase);
        short8 a1 = *(const short8*)(qh + 32 + dbase);
        short8 b0 = *(const short8*)(kh + dbase);
        short8 b1 = *(const short8*)(kh + 32 + dbase);
        f32x4 s = {0.f, 0.f, 0.f, 0.f};
        s = __builtin_amdgcn_mfma_f32_16x16x32_bf16(a0, b0, s, 0, 0, 0);
        s = __builtin_amdgcn_mfma_f32_16x16x32_bf16(a1, b1, s, 0, 0, 0);
        float pr[16];
        #pragma unroll
        for (int kp = 0; kp < 16; ++kp) pr[kp] = pre[h*16 + kp];
        #pragma unroll
        for (int rg = 0; rg < 4; ++rg) {
            int gi = i16*16 + grp*4 + rg;
            int gj = j16*16 + row_l;
            float tv = s[rg]*SCALE + rel[(h*NS + gi)*NS + gj];
            #pragma unroll
            for (int kp = 0; kp < 16; ++kp) acc[kp][rg] += tv * pr[kp];
        }
    }
    int gj = j16*16 + row_l;
    #pragma unroll
    for (int kp = 0; kp < 16; ++kp)
        #pragma unroll
        for (int rg = 0; rg < 4; ++rg) {
            int gi = i16*16 + grp*4 + rg;
            dots[(((b_*HH + kp)*NS) + gi)*NS + gj] = acc[kp][rg];
        }
}

// ---------------- K3 helper: causal mask + exact top-k via ballot binary search + softmax ----------------
template<int NC>
__device__ __forceinline__ void topk_row(const float* __restrict__ rowp,
        float* __restrict__ scRow, int i, int l) {
    float v[NC*4];
    unsigned u[NC*4];
    #pragma unroll
    for (int c = 0; c < NC; ++c) {
        float4 t4 = *(const float4*)(rowp + c*256 + l*4);
        v[c*4+0] = t4.x; v[c*4+1] = t4.y; v[c*4+2] = t4.z; v[c*4+3] = t4.w;
    }
    #pragma unroll
    for (int c = 0; c < NC; ++c) {
        int j0 = c*256 + l*4;
        #pragma unroll
        for (int e = 0; e < 4; ++e)
            if (j0 + e > i) v[c*4+e] = NEGF;
    }
    float m = NEGF;
    #pragma unroll
    for (int e = 0; e < NC*4; ++e) m = fmaxf(m, v[e]);
    #pragma unroll
    for (int o = 32; o; o >>= 1) m = fmaxf(m, __shfl_xor(m, o));
    // ordered-uint transform: monotone map fp32 -> u32
    #pragma unroll
    for (int e = 0; e < NC*4; ++e) {
        unsigned x = __float_as_uint(v[e]);
        u[e] = x ^ ((unsigned)(((int)x) >> 31) | 0x80000000u);
    }
    // 32-step binary search: thr = max{t : count(u >= t) >= KTOP}  == u(kth) exactly (ties incl.)
    unsigned thr = 0u;
    for (int bit = 31; bit >= 0; --bit) {
        unsigned cand = thr | (1u << bit);
        int cnt = 0;
        #pragma unroll
        for (int e = 0; e < NC*4; ++e)
            cnt += __popcll(__ballot(u[e] >= cand));
        if (cnt >= KTOP) thr = cand;
    }
    float ssum = 0.f;
    #pragma unroll
    for (int e = 0; e < NC*4; ++e) {
        float ev = (u[e] >= thr) ? __expf(v[e] - m) : 0.f;
        v[e] = ev; ssum += ev;
    }
    #pragma unroll
    for (int o = 32; o; o >>= 1) ssum += __shfl_xor(ssum, o);
    float inv = 1.0f / ssum;
    #pragma unroll
    for (int c = 0; c < NC; ++c) {
        float4 o4;
        o4.x = v[c*4+0] * inv; o4.y = v[c*4+1] * inv;
        o4.z = v[c*4+2] * inv; o4.w = v[c*4+3] * inv;
        *(float4*)(scRow + c*256 + l*4) = o4;
    }
    float4 z4 = {0.f, 0.f, 0.f, 0.f};
    #pragma unroll
    for (int c = NC; c < 4; ++c)
        *(float4*)(scRow + c*256 + l*4) = z4;
}

// ---------------- K3: topk+softmax per head-wave; post-mix written bf16 packed in place ----------------
// bf16 P row (b,kp,i) occupies the FIRST 2048 bytes of the fp32 dots row (b,kp,i).
__global__ __launch_bounds__(1024, 4) void k3_topk(float* __restrict__ dots,
        const float* __restrict__ post) {
    __shared__ float sc[HH][NS];
    __shared__ float postS[HH][HH];
    int t = threadIdx.x;
    int bi = blockIdx.x;
    int b_ = bi >> 10, i = bi & 1023;
    if (t < 256) postS[t >> 4][t & 15] = post[t];
    int w = t >> 6;
    int l = t & 63;
    const float* rowp = dots + ((size_t)((b_*HH + w)*NS + i))*NS;
    int nc = (i >> 8) + 1;
    if (nc == 1)      topk_row<1>(rowp, sc[w], i, l);
    else if (nc == 2) topk_row<2>(rowp, sc[w], i, l);
    else if (nc == 3) topk_row<3>(rowp, sc[w], i, l);
    else              topk_row<4>(rowp, sc[w], i, l);
    __syncthreads();
    ushort_t* pb = (ushort_t*)dots;
    float a16[HH];
    #pragma unroll
    for (int h = 0; h < HH; ++h) a16[h] = sc[h][t];
    #pragma unroll
    for (int kp = 0; kp < HH; ++kp) {
        float o = 0.f;
        #pragma unroll
        for (int h = 0; h < HH; ++h) o += a16[h] * postS[h][kp];
        pb[(((size_t)(b_*HH + kp)*NS + i)*NS << 1) + t] = f2b(o);
    }
}

// ---------------- K5: PV via MFMA, A = packed bf16 P (global), B = vT (global) ----------------
__global__ __launch_bounds__(256) void k5_pv(const ushort_t* __restrict__ pb,
        const ushort_t* __restrict__ vT, ushort_t* __restrict__ ao) {
    int t = threadIdx.x;
    int lane = t & 63, w = t >> 6;
    int bh = blockIdx.y;
    int i0 = blockIdx.x * 64;
    int row_l = lane & 15, grp = lane >> 4;
    int irow = i0 + w*16 + row_l;
    const ushort_t* pA = pb + (((size_t)bh*NS + irow)*NS << 1);
    const ushort_t* vB = vT + ((size_t)bh*DH + row_l)*NS;
    f32x4 acc[4];
    f32x4 zz = {0.f, 0.f, 0.f, 0.f};
    #pragma unroll
    for (int ni = 0; ni < 4; ++ni) acc[ni] = zz;
    int nsteps = (i0 + 64) >> 5;
    for (int s = 0; s < nsteps; ++s) {
        int j0 = s*32 + grp*8;
        short8 a = *(const short8*)(pA + j0);
        #pragma unroll
        for (int ni = 0; ni < 4; ++ni) {
            short8 b = *(const short8*)(vB + ni*16*NS + j0);
            acc[ni] = __builtin_amdgcn_mfma_f32_16x16x32_bf16(a, b, acc[ni], 0, 0, 0);
        }
    }
    #pragma unroll
    for (int ni = 0; ni < 4; ++ni)
        #pragma unroll
        for (int rg = 0; rg < 4; ++rg)
            ao[((size_t)bh*NS + i0 + w*16 + grp*4 + rg)*DH + ni*16 + row_l] = f2b(acc[ni][rg]);
}

// ---------------- K6: output projection, bf16 MFMA ----------------
__global__ __launch_bounds__(256) void k6_mfma(const ushort_t* __restrict__ aob,
        const ushort_t* __restrict__ Wot, const float* __restrict__ bout,
        float* __restrict__ y) {
    __shared__ ushort_t As[128*40];
    __shared__ ushort_t Bs[128*40];
    int t = threadIdx.x;
    int lane = t & 63, w = t >> 6;
    int wm = w >> 1, wn = w & 1;
    int row_l = lane & 15, grp = lane >> 4;
    int row0 = blockIdx.y * 128, col0 = blockIdx.x * 128;
    f32x4 acc[4][4];
    f32x4 zz = {0.f, 0.f, 0.f, 0.f};
    #pragma unroll
    for (int mi = 0; mi < 4; ++mi)
        #pragma unroll
        for (int ni = 0; ni < 4; ++ni) acc[mi][ni] = zz;
    for (int k0 = 0; k0 < 1024; k0 += 32) {
        #pragma unroll
        for (int e = 0; e < 2; ++e) {
            int slot = t + 256*e;
            int r = slot >> 2, kbk = slot & 3;
            int grow = row0 + r;
            int b_ = grow >> 10, i = grow & 1023;
            int kk0 = k0 + kbk*8;
            int h = kk0 >> 6, d = kk0 & 63;
            short8 vA = *(const short8*)(aob + (((b_*HH + h)*NS) + i)*DH + d);
            *(short8*)(As + r*40 + kbk*8) = vA;
            short8 vB = *(const short8*)(Wot + (col0 + r)*1024 + k0 + kbk*8);
            *(short8*)(Bs + r*40 + kbk*8) = vB;
        }
        __syncthreads();
        short8 a[4], b[4];
        #pragma unroll
        for (int mi = 0; mi < 4; ++mi)
            a[mi] = *(const short8*)(As + (wm*64 + mi*16 + row_l)*40 + grp*8);
        #pragma unroll
        for (int ni = 0; ni < 4; ++ni)
            b[ni] = *(const short8*)(Bs + (wn*64 + ni*16 + row_l)*40 + grp*8);
        #pragma unroll
        for (int mi = 0; mi < 4; ++mi)
            #pragma unroll
            for (int ni = 0; ni < 4; ++ni)
                acc[mi][ni] = __builtin_amdgcn_mfma_f32_16x16x32_bf16(
                    a[mi], b[ni], acc[mi][ni], 0, 0, 0);
        __syncthreads();
    }
    #pragma unroll
    for (int mi = 0; mi < 4; ++mi)
        #pragma unroll
        for (int ni = 0; ni < 4; ++ni)
            #pragma unroll
            for (int rg = 0; rg < 4; ++rg) {
                int grow = row0 + wm*64 + mi*16 + grp*4 + rg;
                int gcol = col0 + wn*64 + ni*16 + row_l;
                y[grow*1024 + gcol] = acc[mi][ni][rg] + bout[gcol];
            }
}

extern "C" void kernel_launch(void* const* d_in, const int* in_sizes, int n_in,
                              void* d_out, int out_size, void* d_ws, size_t ws_size,
                              hipStream_t stream) {
    const float* x    = (const float*)d_in[0];
    const float* rel  = (const float*)d_in[1];
    const float* Wq   = (const float*)d_in[2];
    const float* Wkv  = (const float*)d_in[3];
    const float* pre  = (const float*)d_in[4];
    const float* post = (const float*)d_in[5];
    const float* Wout = (const float*)d_in[6];
    const float* bout = (const float*)d_in[7];
    float* out = (float*)d_out;

    float* ws = (float*)d_ws;
    // float-unit offsets (total exactly 160 MiB)
    float*    dots = ws;                               // 33,554,432 fu (bf16 P packed in place)
    ushort_t* vb   = (ushort_t*)(ws + 33554432);       // 2,097,152 bf16
    ushort_t* vT   = (ushort_t*)(ws + 34603008);       // 2,097,152 bf16
    ushort_t* qb   = (ushort_t*)(ws + 35651584);       // 2,097,152 bf16
    ushort_t* kbuf = (ushort_t*)(ws + 36700160);       // 2,097,152 bf16
    ushort_t* xb   = (ushort_t*)(ws + 37748736);       // 2,097,152 bf16
    ushort_t* Wt   = (ushort_t*)(ws + 38797312);       // 3,145,728 bf16
    ushort_t* Wot  = (ushort_t*)(ws + 40370176);       // 1,048,576 bf16
    ushort_t* aob  = (ushort_t*)(ws + 40894464);       // 2,097,152 bf16

    k0_cvt<<<1024, 256, 0, stream>>>(x, xb, 262144);
    k0_tr<<<dim3(32, 32), 256, 0, stream>>>(Wq, Wt, 1024);
    k0_tr<<<dim3(64, 32), 256, 0, stream>>>(Wkv, Wt + 1024*1024, 2048);
    k0_tr<<<dim3(32, 32), 256, 0, stream>>>(Wout, Wot, 1024);
    k1_mfma<<<dim3(24, 16), 256, 0, stream>>>(xb, Wt, qb, kbuf, vb);
    k4_vt<<<dim3(2, 32, 32), 256, 0, stream>>>(vb, vT);
    k2_scores<<<dim3(1040), 256, 0, stream>>>(qb, kbuf, rel, pre, dots);
    k3_topk<<<dim3(2048), 1024, 0, stream>>>(dots, post);
    k5_pv<<<dim3(16, 32), 256, 0, stream>>>((const ushort_t*)dots, vT, aob);
    k6_mfma<<<dim3(8, 16), 256, 0, stream>>>(aob, Wot, bout, out);
}